// Round 3
// baseline (492.041 us; speedup 1.0000x reference)
//
#include <hip/hip_runtime.h>
#include <math.h>

// LSTM fused: H=32, D=1, B=4096, T=1024 — R15: R13 frame + poly-exp2 + Newton-rcp.
//
// R12-R14 law (additive-pipe model, fits all 3 rounds ±5%): per-SIMD wall =
// VALU-busy + MFMA-busy + stalls; MFMA and VALU do NOT overlap per-SIMD.
// Trans ops (exp2/rcp) fit at ~24 cyc/wave64 -> 14 trans/wave-step = 336 cyc
// = 43% of R13's wall. R14's 2-waves/SIMD was null because busy is additive
// and BPW=2 doubled MFMA work per batch.
// R15:
//   1. Revert to BPW=4 (R13): 8 MFMA serve 4 batches (MFMA floor 39/batch).
//   2. nrcp: magic-seed + 2 Newton = 5 VALU ops (10 cyc) vs rcp ~24.
//      Seed valid for all positive args (denoms > 1 always). err 6e-6.
//   3. pexp2: rndne + deg-4 Horner + ldexp = 8 VALU ops (16 cyc) vs ~24.
//      rel err 4e-5 << fp16-h quantization. Finite for all our args.
//   4. x chunk pre-converted to f32 (8 cvts hoisted per 8 steps).
// Everything else identical to R13: transposed MFMA (A=h, B=pair-permuted
// scaled W_hh), zero extraction (acc[tau][0]), 4 packed bpermutes, rational
// fused acts, 256 blocks x 4 waves = 1 wave/SIMD.

#define HH 32
#define TT 1024
#define BPW 4               // batches per wave
#define WPB 4               // waves per block
#define BPB (BPW * WPB)     // 16
#define NT 256

typedef _Float16 half8 __attribute__((ext_vector_type(8)));
typedef float    f32x4 __attribute__((ext_vector_type(4)));
typedef int      int4v __attribute__((ext_vector_type(4)));

// Newton reciprocal: 5 VALU ops, rel err ~6e-6. Valid for x > 0 (our denoms > 1).
__device__ __forceinline__ float nrcp(float x) {
    float y = __builtin_bit_cast(float, 0x7EF311C3 - __builtin_bit_cast(int, x));
    y = y * (2.0f - x * y);
    y = y * (2.0f - x * y);
    return y;
}

// Polynomial exp2: 8 VALU ops, rel err ~4e-5 on full range via ldexp.
__device__ __forceinline__ float pexp2(float x) {
    const float n = rintf(x);            // v_rndne_f32
    const float f = x - n;               // f in [-0.5, 0.5]
    float p = fmaf(f, 0.0096181291f, 0.0555041087f);
    p = fmaf(f, p, 0.2402265070f);
    p = fmaf(f, p, 0.6931471806f);
    p = fmaf(f, p, 1.0f);
    return ldexpf(p, (int)n);            // v_ldexp_f32
}

__global__ __attribute__((amdgpu_flat_work_group_size(NT, NT),
                          amdgpu_waves_per_eu(1, 2)))
void lstm_vp(const float* __restrict__ x,
             const float* __restrict__ W_ih,
             const float* __restrict__ W_hh,
             const float* __restrict__ b_ih,
             const float* __restrict__ b_hh,
             const float* __restrict__ fc_W,
             const float* __restrict__ fc_b,
             float* __restrict__ out)
{
    __shared__ _Float16 xw[WPB][BPW * TT];   // 32 KB: x fp16, wave-private

    const int tid  = threadIdx.x;
    const int wv   = tid >> 6;
    const int lane = tid & 63;
    const int q    = lane >> 4;          // batch index within wave (0..3)
    const int n    = lane & 15;          // unit-pair index (0..15)
    const int ue   = 2 * n;
    const int uo   = ue + 1;
    const int gb0  = blockIdx.x * BPB + wv * BPW;

    // ---- stage this wave's 4 x-rows into LDS as fp16 (wave-private) ----
    {
        const float4* xg = (const float4*)(x + (size_t)gb0 * TT);
        #pragma unroll
        for (int it = 0; it < (BPW * TT / 4) / 64; ++it) {
            const float4 v = xg[it * 64 + lane];
            _Float16* dst = &xw[wv][(it * 64 + lane) * 4];
            dst[0] = (_Float16)v.x; dst[1] = (_Float16)v.y;
            dst[2] = (_Float16)v.z; dst[3] = (_Float16)v.w;
        }
    }

    const float L1 = 1.4426950408889634f;    // log2(e)

    // ---- B-fragments: pair-permuted weights, pre-scaled by -L (i,f,o)
    //      or -2L (g). Tile tau=2g+pp, col n = W_hh row 32g+2n+pp;
    //      lane supplies B[k=8q+j][n]. ----
    half8 wf[8];
    #pragma unroll
    for (int g = 0; g < 4; ++g) {
        const float s = (g == 2) ? -2.0f * L1 : -L1;
        #pragma unroll
        for (int pp = 0; pp < 2; ++pp) {
            const float* arow = W_hh + (size_t)(32 * g + 2 * n + pp) * HH + 8 * q;
            #pragma unroll
            for (int j = 0; j < 8; ++j)
                wf[2 * g + pp][j] = (_Float16)(arow[j] * s);
        }
    }

    // ---- per-lane act constants (same -L/-2L scaling folded in) ----
    float wxE[4], bbE[4], wxO[4], bbO[4];
    #pragma unroll
    for (int g = 0; g < 4; ++g) {
        const float s = (g == 2) ? -2.0f * L1 : -L1;
        wxE[g] = W_ih[g * HH + ue] * s;
        bbE[g] = (b_ih[g * HH + ue] + b_hh[g * HH + ue]) * s;
        wxO[g] = W_ih[g * HH + uo] * s;
        bbO[g] = (b_ih[g * HH + uo] + b_hh[g * HH + uo]) * s;
    }

    // bpermute byte base: A-frag int i comes from lane 16*(n>>2) + 4q + i
    const int bpb = (((n >> 2) << 4) + 4 * q) << 2;

    float ce = 0.0f, co = 0.0f, he = 0.0f, ho = 0.0f;
    int pki = 0;                          // packed (h_ue, h_uo) fp16x2

    const half8* xp = (const half8*)&xw[wv][q * TT];
    half8 xcur = xp[0];

    #pragma unroll 1
    for (int tc = 0; tc < TT / 8; ++tc) {
        const half8 xv8 = xcur;
        xcur = xp[(tc + 1) & (TT / 8 - 1)];   // prefetch next chunk (off-chain)

        // pre-convert the chunk to f32 once (off the serial chain)
        float xf[8];
        #pragma unroll
        for (int j = 0; j < 8; ++j) xf[j] = (float)xv8[j];

        #pragma unroll
        for (int tt = 0; tt < 8; ++tt) {
            // ---- h exchange: A-frag = packed h pairs from 4 source lanes ----
            const int r0 = __builtin_amdgcn_ds_bpermute(bpb,      pki);
            const int r1 = __builtin_amdgcn_ds_bpermute(bpb + 4,  pki);
            const int r2 = __builtin_amdgcn_ds_bpermute(bpb + 8,  pki);
            const int r3 = __builtin_amdgcn_ds_bpermute(bpb + 12, pki);

            // ---- preact input part, OFF the chain ----
            const float xv = xf[tt];
            float qE[4], qO[4];
            #pragma unroll
            for (int g = 0; g < 4; ++g) {
                qE[g] = fmaf(xv, wxE[g], bbE[g]);
                qO[g] = fmaf(xv, wxO[g], bbO[g]);
            }

            int4v ai; ai[0] = r0; ai[1] = r1; ai[2] = r2; ai[3] = r3;
            const half8 av = __builtin_bit_cast(half8, ai);

            const f32x4 zero = {0.0f, 0.0f, 0.0f, 0.0f};
            f32x4 acc[8];
            #pragma unroll
            for (int tau = 0; tau < 8; ++tau) {
                acc[tau] = __builtin_amdgcn_mfma_f32_16x16x32_f16(
                               av, wf[tau], zero, 0, 0, 0);
                asm("" : "+v"(acc[tau]));   // pin quad to arch VGPRs
            }

            // ---- exp2 args, fixed element 0: zero extraction ----
            const float aEi = acc[0][0] + qE[0];
            const float aOi = acc[1][0] + qO[0];
            const float aEf = acc[2][0] + qE[1];
            const float aOf = acc[3][0] + qO[1];
            const float aEg = acc[4][0] + qE[2];
            const float aOg = acc[5][0] + qO[2];
            const float aEo = acc[6][0] + qE[3];
            const float aOo = acc[7][0] + qO[3];

            const float eaE = pexp2(aEi);   // e^-i
            const float eaO = pexp2(aOi);
            const float ebE = pexp2(aEf);   // e^-f
            const float ebO = pexp2(aOf);
            const float edE = pexp2(aEg);   // e^-2g
            const float edO = pexp2(aOg);
            const float eeE = pexp2(aEo);   // e^-o
            const float eeO = pexp2(aOo);

            // ---- c' = (c*u*v + w*(2-v)) / (u*v*w); Newton rcp ----
            const float uE = 1.0f + eaE, vE = 1.0f + edE, wE = 1.0f + ebE;
            const float uO = 1.0f + eaO, vO = 1.0f + edO, wO = 1.0f + ebO;
            const float uvE = uE * vE;
            const float uvO = uO * vO;
            const float numE = fmaf(ce, uvE, wE * (2.0f - vE));
            const float numO = fmaf(co, uvO, wO * (2.0f - vO));
            ce = numE * nrcp(uvE * wE);
            co = numO * nrcp(uvO * wO);
            ce = fminf(fmaxf(ce, -32.0f), 32.0f);   // guard m-overflow
            co = fminf(fmaxf(co, -32.0f), 32.0f);

            // ---- h = (1-m)/((1+e)(1+m)), m = e^-2c ----
            const float mE = pexp2(ce * (-2.0f * L1));
            const float mO = pexp2(co * (-2.0f * L1));
            he = (1.0f - mE) * nrcp((1.0f + eeE) * (1.0f + mE));
            ho = (1.0f - mO) * nrcp((1.0f + eeO) * (1.0f + mO));

            // ---- pack for next step's exchange ----
            pki = __builtin_bit_cast(int, __builtin_amdgcn_cvt_pkrtz(he, ho));
        }
    }

    // ---- epilogue: out[gb0+q] = fc_W . h + fc_b; reduce over n (bits 0-3) ----
    float pr = he * fc_W[ue] + ho * fc_W[uo];
    pr += __shfl_xor(pr, 1, 64);
    pr += __shfl_xor(pr, 2, 64);
    pr += __shfl_xor(pr, 4, 64);
    pr += __shfl_xor(pr, 8, 64);
    if (n == 0)
        out[gb0 + q] = pr + fc_b[0];
}

extern "C" void kernel_launch(void* const* d_in, const int* in_sizes, int n_in,
                              void* d_out, int out_size, void* d_ws, size_t ws_size,
                              hipStream_t stream) {
    const float* x    = (const float*)d_in[0];
    const float* W_ih = (const float*)d_in[1];
    const float* W_hh = (const float*)d_in[2];
    const float* b_ih = (const float*)d_in[3];
    const float* b_hh = (const float*)d_in[4];
    const float* fc_W = (const float*)d_in[5];
    const float* fc_b = (const float*)d_in[6];
    float* out = (float*)d_out;

    const int B = in_sizes[0] / TT;   // 4096 (D == 1)
    dim3 grid(B / BPB), block(NT);
    lstm_vp<<<grid, block, 0, stream>>>(x, W_ih, W_hh, b_ih, b_hh,
                                        fc_W, fc_b, out);
}

// Round 4
// 362.609 us; speedup vs baseline: 1.3569x; 1.3569x over previous
//
#include <hip/hip_runtime.h>
#include <math.h>

// LSTM fused: H=32, D=1, B=4096, T=1024 — R16: R13 frame + packed-f32 act math.
//
// R12-R15 law (global fit, 3 rounds ±2%): per-SIMD busy = 5 cyc/plain-VALU
// + 11 cyc/hw-trans + ~17 cyc/MFMA, additive, 1 wave/SIMD. R15's poly
// exp2/Newton rcp was a big loss (hw trans only ~2x a plain op) -> reverted.
// MFMA count (8/wave-step) is at the structural floor: 512 gate-values
// needed, dup-4 rows give 64 useful/MFMA. 16-batch A-packing would leave
// 3/4 of the chip idle (256 waves). Remaining lever: plain-op count.
// R16:
//   1. Entire act block in float2 (E,O) ext-vectors -> v_pk_fma_f32 /
//      v_pk_add_f32 / v_pk_mul_f32 (full-rate packed f32 on CDNA).
//      Plain ops/wave-step 51 -> ~31. Trans stay scalar (no packed exp2).
//   2. c-clamp (2 ops) -> single pk_min guard on the m-exponent (the only
//      overflow path: c << 0 -> m = e^{-2c} = inf -> NaN).
// Everything else identical to R13: transposed MFMA (A=h via 4 packed
// bpermutes, B=pair-permuted -L/-2L-scaled W_hh), zero extraction
// (acc[tau][0]), rational fused acts, 256 blocks x 4 waves = 1 wave/SIMD.

#define HH 32
#define TT 1024
#define BPW 4               // batches per wave
#define WPB 4               // waves per block
#define BPB (BPW * WPB)     // 16
#define NT 256

typedef _Float16 half8 __attribute__((ext_vector_type(8)));
typedef float    f32x4 __attribute__((ext_vector_type(4)));
typedef float    f32x2 __attribute__((ext_vector_type(2)));
typedef int      int4v __attribute__((ext_vector_type(4)));

__global__ __attribute__((amdgpu_flat_work_group_size(NT, NT),
                          amdgpu_waves_per_eu(1, 2)))
void lstm_vp(const float* __restrict__ x,
             const float* __restrict__ W_ih,
             const float* __restrict__ W_hh,
             const float* __restrict__ b_ih,
             const float* __restrict__ b_hh,
             const float* __restrict__ fc_W,
             const float* __restrict__ fc_b,
             float* __restrict__ out)
{
    __shared__ _Float16 xw[WPB][BPW * TT];   // 32 KB: x fp16, wave-private

    const int tid  = threadIdx.x;
    const int wv   = tid >> 6;
    const int lane = tid & 63;
    const int q    = lane >> 4;          // batch index within wave (0..3)
    const int n    = lane & 15;          // unit-pair index (0..15)
    const int ue   = 2 * n;
    const int uo   = ue + 1;
    const int gb0  = blockIdx.x * BPB + wv * BPW;

    // ---- stage this wave's 4 x-rows into LDS as fp16 (wave-private) ----
    {
        const float4* xg = (const float4*)(x + (size_t)gb0 * TT);
        #pragma unroll
        for (int it = 0; it < (BPW * TT / 4) / 64; ++it) {
            const float4 v = xg[it * 64 + lane];
            _Float16* dst = &xw[wv][(it * 64 + lane) * 4];
            dst[0] = (_Float16)v.x; dst[1] = (_Float16)v.y;
            dst[2] = (_Float16)v.z; dst[3] = (_Float16)v.w;
        }
    }

    const float L1 = 1.4426950408889634f;    // log2(e)

    // ---- B-fragments: pair-permuted weights, pre-scaled by -L (i,f,o)
    //      or -2L (g). Tile tau=2g+pp, col n = W_hh row 32g+2n+pp;
    //      lane supplies B[k=8q+j][n]. ----
    half8 wf[8];
    #pragma unroll
    for (int g = 0; g < 4; ++g) {
        const float s = (g == 2) ? -2.0f * L1 : -L1;
        #pragma unroll
        for (int pp = 0; pp < 2; ++pp) {
            const float* arow = W_hh + (size_t)(32 * g + 2 * n + pp) * HH + 8 * q;
            #pragma unroll
            for (int j = 0; j < 8; ++j)
                wf[2 * g + pp][j] = (_Float16)(arow[j] * s);
        }
    }

    // ---- per-lane act constants as (E,O) float2 pairs ----
    f32x2 wx2[4], bb2[4];
    #pragma unroll
    for (int g = 0; g < 4; ++g) {
        const float s = (g == 2) ? -2.0f * L1 : -L1;
        wx2[g].x = W_ih[g * HH + ue] * s;
        wx2[g].y = W_ih[g * HH + uo] * s;
        bb2[g].x = (b_ih[g * HH + ue] + b_hh[g * HH + ue]) * s;
        bb2[g].y = (b_ih[g * HH + uo] + b_hh[g * HH + uo]) * s;
    }

    // bpermute byte base: A-frag int i comes from lane 16*(n>>2) + 4q + i
    const int bpb = (((n >> 2) << 4) + 4 * q) << 2;

    const f32x2 one  = {1.0f, 1.0f};
    const f32x2 two  = {2.0f, 2.0f};
    const f32x2 nl2  = {-2.0f * L1, -2.0f * L1};
    const f32x2 mcap = {126.0f, 126.0f};

    f32x2 c2 = {0.0f, 0.0f};
    f32x2 h2 = {0.0f, 0.0f};
    int pki = 0;                          // packed (h_ue, h_uo) fp16x2

    const half8* xp = (const half8*)&xw[wv][q * TT];
    half8 xcur = xp[0];

    #pragma unroll 1
    for (int tc = 0; tc < TT / 8; ++tc) {
        const half8 xv8 = xcur;
        xcur = xp[(tc + 1) & (TT / 8 - 1)];   // prefetch next chunk (off-chain)

        // pre-convert the chunk to f32 once (off the serial chain)
        float xf[8];
        #pragma unroll
        for (int j = 0; j < 8; ++j) xf[j] = (float)xv8[j];

        #pragma unroll
        for (int tt = 0; tt < 8; ++tt) {
            // ---- h exchange: A-frag = packed h pairs from 4 source lanes ----
            const int r0 = __builtin_amdgcn_ds_bpermute(bpb,      pki);
            const int r1 = __builtin_amdgcn_ds_bpermute(bpb + 4,  pki);
            const int r2 = __builtin_amdgcn_ds_bpermute(bpb + 8,  pki);
            const int r3 = __builtin_amdgcn_ds_bpermute(bpb + 12, pki);

            // ---- preact input part, OFF the chain (packed E/O) ----
            f32x2 xs; xs.x = xf[tt]; xs.y = xf[tt];
            f32x2 q2[4];
            #pragma unroll
            for (int g = 0; g < 4; ++g)
                q2[g] = __builtin_elementwise_fma(xs, wx2[g], bb2[g]);

            int4v ai; ai[0] = r0; ai[1] = r1; ai[2] = r2; ai[3] = r3;
            const half8 av = __builtin_bit_cast(half8, ai);

            const f32x4 zero = {0.0f, 0.0f, 0.0f, 0.0f};
            f32x4 acc[8];
            #pragma unroll
            for (int tau = 0; tau < 8; ++tau) {
                acc[tau] = __builtin_amdgcn_mfma_f32_16x16x32_f16(
                               av, wf[tau], zero, 0, 0, 0);
                asm("" : "+v"(acc[tau]));   // pin quad to arch VGPRs
            }

            // ---- exp2 args, fixed element 0: zero extraction ----
            const float aEi = acc[0][0] + q2[0].x;
            const float aOi = acc[1][0] + q2[0].y;
            const float aEf = acc[2][0] + q2[1].x;
            const float aOf = acc[3][0] + q2[1].y;
            const float aEg = acc[4][0] + q2[2].x;
            const float aOg = acc[5][0] + q2[2].y;
            const float aEo = acc[6][0] + q2[3].x;
            const float aOo = acc[7][0] + q2[3].y;

            f32x2 ea2, eb2, ed2, ee2;
            ea2.x = __builtin_amdgcn_exp2f(aEi);   // e^-i
            ea2.y = __builtin_amdgcn_exp2f(aOi);
            eb2.x = __builtin_amdgcn_exp2f(aEf);   // e^-f
            eb2.y = __builtin_amdgcn_exp2f(aOf);
            ed2.x = __builtin_amdgcn_exp2f(aEg);   // e^-2g
            ed2.y = __builtin_amdgcn_exp2f(aOg);
            ee2.x = __builtin_amdgcn_exp2f(aEo);   // e^-o
            ee2.y = __builtin_amdgcn_exp2f(aOo);

            // ---- c' = (c*u*v + w*(2-v)) / (u*v*w); packed, one rcp/side ----
            const f32x2 u2  = one + ea2;
            const f32x2 v2  = one + ed2;
            const f32x2 w2  = one + eb2;
            const f32x2 uv2 = u2 * v2;
            const f32x2 num2 = __builtin_elementwise_fma(c2, uv2, w2 * (two - v2));
            const f32x2 den2 = uv2 * w2;
            f32x2 rc2;
            rc2.x = __builtin_amdgcn_rcpf(den2.x);
            rc2.y = __builtin_amdgcn_rcpf(den2.y);
            c2 = num2 * rc2;

            // ---- h = (1-m)/((1+e)(1+m)), m = e^-2c; guard only m-overflow ----
            f32x2 marg = __builtin_elementwise_min(c2 * nl2, mcap);
            f32x2 m2;
            m2.x = __builtin_amdgcn_exp2f(marg.x);
            m2.y = __builtin_amdgcn_exp2f(marg.y);
            const f32x2 hn2 = one - m2;
            const f32x2 hd2 = (one + ee2) * (one + m2);
            f32x2 hr2;
            hr2.x = __builtin_amdgcn_rcpf(hd2.x);
            hr2.y = __builtin_amdgcn_rcpf(hd2.y);
            h2 = hn2 * hr2;

            // ---- pack for next step's exchange ----
            pki = __builtin_bit_cast(int, __builtin_amdgcn_cvt_pkrtz(h2.x, h2.y));
        }
    }

    // ---- epilogue: out[gb0+q] = fc_W . h + fc_b; reduce over n (bits 0-3) ----
    float pr = h2.x * fc_W[ue] + h2.y * fc_W[uo];
    pr += __shfl_xor(pr, 1, 64);
    pr += __shfl_xor(pr, 2, 64);
    pr += __shfl_xor(pr, 4, 64);
    pr += __shfl_xor(pr, 8, 64);
    if (n == 0)
        out[gb0 + q] = pr + fc_b[0];
}

extern "C" void kernel_launch(void* const* d_in, const int* in_sizes, int n_in,
                              void* d_out, int out_size, void* d_ws, size_t ws_size,
                              hipStream_t stream) {
    const float* x    = (const float*)d_in[0];
    const float* W_ih = (const float*)d_in[1];
    const float* W_hh = (const float*)d_in[2];
    const float* b_ih = (const float*)d_in[3];
    const float* b_hh = (const float*)d_in[4];
    const float* fc_W = (const float*)d_in[5];
    const float* fc_b = (const float*)d_in[6];
    float* out = (float*)d_out;

    const int B = in_sizes[0] / TT;   // 4096 (D == 1)
    dim3 grid(B / BPB), block(NT);
    lstm_vp<<<grid, block, 0, stream>>>(x, W_ih, W_hh, b_ih, b_hh,
                                        fc_W, fc_b, out);
}

// Round 5
// 315.079 us; speedup vs baseline: 1.5616x; 1.1509x over previous
//
#include <hip/hip_runtime.h>
#include <math.h>

// LSTM fused: H=32, D=1, B=4096, T=1024 — R17: coupled wave-pair parity split.
//
// R13-R16 law: wall pinned at ~780 cyc/step = VALU busy 426 (trans 14x22=308
// is the floor, per-state & lane-dense) + MFMA 136 + DS 30 + ~190 chain
// stall. Instruction cuts are null (R16: busy -60, wall +0): stall-bound at
// 1 wave/SIMD. R14 proved 2 waves/SIMD kill the stall but its BPW=2 doubled
// MFMA/batch. R17: 2 waves/SIMD at FULL MFMA density via pair-split:
//   - Block = 128 thr = 2 waves sharing 4 batches. Wave P owns parity-P
//     units (u=2n+P): 1 state/lane -> 7 trans/wave-step (SIMD total same),
//     4 MFMA tiles/wave (tau=2g+P) -> 8 tiles per 4 batches (= R16).
//   - h-exchange: fp16 h -> double-buffered LDS slot (ds_write_b16),
//     one __syncthreads per step, A-frag = single ds_read_b128
//     (units 8q..8q+7 of batch n>>2). bpermutes + packing gone.
//   - Wave i -> SIMD i%4: paired waves sit on different SIMDs; each SIMD
//     hosts 2 independent-batch waves (different blocks) = R14's
//     stall-filling config without its MFMA tax.
// Acts unchanged (R13/R16 rational form, scalar now — 1 state/lane):
// c' = (c*u*v + w*(2-v))/(u*v*w), h = (1-m)/((1+e)(1+m)), -L/-2L folded.
// 1024 blocks x 2 waves, 4 blocks/CU, 8.75 KB LDS/block.

#define HH 32
#define TT 1024
#define BPB 4               // batches per block (= per wave pair)
#define NT 128

typedef _Float16 half8 __attribute__((ext_vector_type(8)));
typedef float    f32x4 __attribute__((ext_vector_type(4)));

__global__ __attribute__((amdgpu_flat_work_group_size(NT, NT),
                          amdgpu_waves_per_eu(2, 2)))
void lstm_vp(const float* __restrict__ x,
             const float* __restrict__ W_ih,
             const float* __restrict__ W_hh,
             const float* __restrict__ b_ih,
             const float* __restrict__ b_hh,
             const float* __restrict__ fc_W,
             const float* __restrict__ fc_b,
             float* __restrict__ out)
{
    __shared__ _Float16 xw[BPB * TT];                 // 8 KB: x fp16
    __shared__ __align__(16) _Float16 hx[2][BPB][HH]; // 512 B: h dbuf
    __shared__ float fo[BPB];                         // epilogue partials

    const int tid  = threadIdx.x;
    const int P    = tid >> 6;           // wave parity: unit 2n+P
    const int lane = tid & 63;
    const int q    = lane >> 4;          // batch index within block (0..3)
    const int n    = lane & 15;          // unit-pair index (0..15)
    const int u    = 2 * n + P;          // owned unit
    const int gb0  = blockIdx.x * BPB;

    // ---- stage the block's 4 x-rows into LDS as fp16 (both waves) ----
    {
        const float4* xg = (const float4*)(x + (size_t)gb0 * TT);
        #pragma unroll
        for (int it = 0; it < (BPB * TT / 4) / NT; ++it) {
            const int idx = it * NT + tid;
            const float4 v = xg[idx];
            _Float16* dst = &xw[idx * 4];
            dst[0] = (_Float16)v.x; dst[1] = (_Float16)v.y;
            dst[2] = (_Float16)v.z; dst[3] = (_Float16)v.w;
        }
    }

    const float L1 = 1.4426950408889634f;    // log2(e)

    // ---- B-fragments: this wave's parity tiles only (tau = 2g+P).
    //      Col n = W_hh row 32g+2n+P; lane supplies B[k=8q+j][n].
    //      Pre-scaled by -L (i,f,o) / -2L (g). ----
    half8 wf[4];
    #pragma unroll
    for (int g = 0; g < 4; ++g) {
        const float s = (g == 2) ? -2.0f * L1 : -L1;
        const float* arow = W_hh + (size_t)(32 * g + 2 * n + P) * HH + 8 * q;
        #pragma unroll
        for (int j = 0; j < 8; ++j)
            wf[g][j] = (_Float16)(arow[j] * s);
    }

    // ---- per-lane act constants for the single owned unit u ----
    float wx[4], bb[4];
    #pragma unroll
    for (int g = 0; g < 4; ++g) {
        const float s = (g == 2) ? -2.0f * L1 : -L1;
        wx[g] = W_ih[g * HH + u] * s;
        bb[g] = (b_ih[g * HH + u] + b_hh[g * HH + u]) * s;
    }

    // zero h slot 0 (each lane covers its own state) + staging sync
    hx[0][q][u] = (_Float16)0.0f;
    __syncthreads();

    // A-frag read pointers: units 8q..8q+7 of batch n>>2 (16B, aligned)
    const half8* hr0 = (const half8*)&hx[0][n >> 2][8 * q];
    const half8* hr1 = (const half8*)&hx[1][n >> 2][8 * q];

    float c = 0.0f, h = 0.0f;

    const half8* xp = (const half8*)&xw[q * TT];
    half8 xcur = xp[0];

    #pragma unroll 1
    for (int tc = 0; tc < TT / 8; ++tc) {
        const half8 xv8 = xcur;
        xcur = xp[(tc + 1) & (TT / 8 - 1)];   // prefetch next chunk (off-chain)

        // pre-convert the chunk to f32 once (off the serial chain)
        float xf[8];
        #pragma unroll
        for (int j = 0; j < 8; ++j) xf[j] = (float)xv8[j];

        #pragma unroll
        for (int tt = 0; tt < 8; ++tt) {
            // ---- A-frag: one ds_read_b128 from current slot ----
            const half8 av = (tt & 1) ? *hr1 : *hr0;

            // ---- preact input part, OFF the chain ----
            const float xv = xf[tt];
            float qq[4];
            #pragma unroll
            for (int g = 0; g < 4; ++g)
                qq[g] = fmaf(xv, wx[g], bb[g]);

            const f32x4 zero = {0.0f, 0.0f, 0.0f, 0.0f};
            f32x4 acc[4];
            #pragma unroll
            for (int g = 0; g < 4; ++g) {
                acc[g] = __builtin_amdgcn_mfma_f32_16x16x32_f16(
                             av, wf[g], zero, 0, 0, 0);
                asm("" : "+v"(acc[g]));   // pin quad to arch VGPRs
            }

            // ---- exp2 args, fixed element 0: zero extraction ----
            const float ea = __builtin_amdgcn_exp2f(acc[0][0] + qq[0]); // e^-i
            const float eb = __builtin_amdgcn_exp2f(acc[1][0] + qq[1]); // e^-f
            const float ed = __builtin_amdgcn_exp2f(acc[2][0] + qq[2]); // e^-2g
            const float ee = __builtin_amdgcn_exp2f(acc[3][0] + qq[3]); // e^-o

            // ---- c' = (c*u*v + w*(2-v)) / (u*v*w); one rcp ----
            const float uu = 1.0f + ea, vv = 1.0f + ed, ww = 1.0f + eb;
            const float uv  = uu * vv;
            const float num = fmaf(c, uv, ww * (2.0f - vv));
            c = num * __builtin_amdgcn_rcpf(uv * ww);

            // ---- h = (1-m)/((1+e)(1+m)); guard only the m-overflow ----
            const float marg = fminf(c * (-2.0f * L1), 126.0f);
            const float m = __builtin_amdgcn_exp2f(marg);
            h = (1.0f - m) * __builtin_amdgcn_rcpf((1.0f + ee) * (1.0f + m));

            // ---- publish h for next step, flip slot, sync pair ----
            hx[(tt & 1) ^ 1][q][u] = (_Float16)h;
            __syncthreads();
        }
    }

    // ---- epilogue: out[gb0+q] = fc_W . h + fc_b across the wave pair ----
    float pr = h * fc_W[u];
    pr += __shfl_xor(pr, 1, 64);
    pr += __shfl_xor(pr, 2, 64);
    pr += __shfl_xor(pr, 4, 64);
    pr += __shfl_xor(pr, 8, 64);
    if (P == 1 && n == 0) fo[q] = pr;
    __syncthreads();
    if (P == 0 && n == 0)
        out[gb0 + q] = pr + fo[q] + fc_b[0];
}

extern "C" void kernel_launch(void* const* d_in, const int* in_sizes, int n_in,
                              void* d_out, int out_size, void* d_ws, size_t ws_size,
                              hipStream_t stream) {
    const float* x    = (const float*)d_in[0];
    const float* W_ih = (const float*)d_in[1];
    const float* W_hh = (const float*)d_in[2];
    const float* b_ih = (const float*)d_in[3];
    const float* b_hh = (const float*)d_in[4];
    const float* fc_W = (const float*)d_in[5];
    const float* fc_b = (const float*)d_in[6];
    float* out = (float*)d_out;

    const int B = in_sizes[0] / TT;   // 4096 (D == 1)
    dim3 grid(B / BPB), block(NT);
    lstm_vp<<<grid, block, 0, stream>>>(x, W_ih, W_hh, b_ih, b_hh,
                                        fc_W, fc_b, out);
}